// Round 1
// baseline (1489.351 us; speedup 1.0000x reference)
//
#include <hip/hip_runtime.h>

#define DD 64

// ---------------- count in-degree (once; shared by both convs) ----------------
__global__ void k_count(const int* __restrict__ ei, int n_edges, int* __restrict__ cnt) {
    int e = blockIdx.x * blockDim.x + threadIdx.x;
    if (e < n_edges) {
        int dst = ei[n_edges + e];   // edge_index[1] = target
        atomicAdd(&cnt[dst], 1);
    }
}

// ---------------- h0 = x @ W^T + b  (per-node, W^T staged in LDS) ----------------
__global__ void k_lin(const float* __restrict__ x, const float* __restrict__ W,
                      const float* __restrict__ b, float* __restrict__ out, int n_nodes) {
    __shared__ float Wt[DD * DD];   // Wt[k*64+d] = W[d*64+k]
    __shared__ float xs[4][DD];
    int t = threadIdx.x;
    for (int i = t; i < DD * DD; i += 256) {
        int k = i >> 6, d = i & 63;
        Wt[i] = W[d * DD + k];
    }
    int g = t >> 6, d = t & 63;
    int n = blockIdx.x * 4 + g;
    if (n < n_nodes) xs[g][d] = x[(size_t)n * DD + d];
    __syncthreads();
    if (n >= n_nodes) return;
    float acc = b[d];
    #pragma unroll 8
    for (int k = 0; k < DD; ++k) acc += xs[g][k] * Wt[k * DD + d];
    out[(size_t)n * DD + d] = acc;
}

// ---------------- scatter-add aggregation: one wave per edge ----------------
__global__ void k_agg(const float* __restrict__ h, const int* __restrict__ ei,
                      int n_edges, float* __restrict__ sum) {
    unsigned tid = blockIdx.x * 256u + threadIdx.x;
    int e = (int)(tid >> 6);
    int d = (int)(tid & 63u);
    if (e >= n_edges) return;
    int src = ei[e];             // edge_index[0] = source
    int dst = ei[n_edges + e];   // edge_index[1] = target
    float v = h[(size_t)src * DD + d];
    unsafeAtomicAdd(&sum[(size_t)dst * DD + d], v);
}

// ------- h_out = [relu]( (sum/max(cnt,1)) @ Wl^T + bl + h @ Wr^T ) -------
__global__ void k_conv(const float* __restrict__ sum, const int* __restrict__ cnt,
                       const float* __restrict__ h,
                       const float* __restrict__ Wl, const float* __restrict__ bl,
                       const float* __restrict__ Wr,
                       float* __restrict__ out, int n_nodes, int do_relu) {
    __shared__ float Wlt[DD * DD];
    __shared__ float Wrt[DD * DD];
    __shared__ float as[4][DD];
    __shared__ float hs[4][DD];
    int t = threadIdx.x;
    for (int i = t; i < DD * DD; i += 256) {
        int k = i >> 6, d = i & 63;
        Wlt[i] = Wl[d * DD + k];
        Wrt[i] = Wr[d * DD + k];
    }
    int g = t >> 6, d = t & 63;
    int n = blockIdx.x * 4 + g;
    if (n < n_nodes) {
        float c = (float)cnt[n];
        float inv = 1.0f / fmaxf(c, 1.0f);
        as[g][d] = sum[(size_t)n * DD + d] * inv;
        hs[g][d] = h[(size_t)n * DD + d];
    }
    __syncthreads();
    if (n >= n_nodes) return;
    float acc = bl[d];
    #pragma unroll 8
    for (int k = 0; k < DD; ++k)
        acc += as[g][k] * Wlt[k * DD + d] + hs[g][k] * Wrt[k * DD + d];
    if (do_relu) acc = fmaxf(acc, 0.0f);
    out[(size_t)n * DD + d] = acc;
}

// ---------------- preds[e] = dot(h[a], h[b]); one wave per label edge ----------------
__global__ void k_pred(const float* __restrict__ h, const int* __restrict__ eli,
                       int n_label, float* __restrict__ out) {
    int t = threadIdx.x;
    int g = t >> 6, d = t & 63;
    int e = blockIdx.x * 4 + g;
    if (e >= n_label) return;
    int a = eli[e];
    int b = eli[n_label + e];
    float v = h[(size_t)a * DD + d] * h[(size_t)b * DD + d];
    #pragma unroll
    for (int o = 32; o > 0; o >>= 1) v += __shfl_down(v, o, 64);
    if (d == 0) out[e] = v;
}

extern "C" void kernel_launch(void* const* d_in, const int* in_sizes, int n_in,
                              void* d_out, int out_size, void* d_ws, size_t ws_size,
                              hipStream_t stream) {
    const float* x     = (const float*)d_in[0];
    const int*   ei    = (const int*)d_in[1];
    const int*   eli   = (const int*)d_in[2];
    const float* W_lin = (const float*)d_in[3];
    const float* b_lin = (const float*)d_in[4];
    const float* Wl1   = (const float*)d_in[5];
    const float* bl1   = (const float*)d_in[6];
    const float* Wr1   = (const float*)d_in[7];
    const float* Wl2   = (const float*)d_in[8];
    const float* bl2   = (const float*)d_in[9];
    const float* Wr2   = (const float*)d_in[10];

    int n_nodes = in_sizes[0] / DD;
    int n_edges = in_sizes[1] / 2;
    int n_label = in_sizes[2] / 2;
    float* out = (float*)d_out;

    char* ws = (char*)d_ws;
    size_t hbytes = (size_t)n_nodes * DD * sizeof(float);
    float* sum = (float*)ws;  ws += hbytes;
    float* hA  = (float*)ws;  ws += hbytes;   // h0, later reused as h2
    float* hB  = (float*)ws;  ws += hbytes;   // h1
    int*   cnt = (int*)ws;    ws += (size_t)n_nodes * sizeof(int);

    int nb_nodes  = (n_nodes + 3) / 4;
    int nb_edge64 = (int)(((long)n_edges * 64 + 255) / 256);
    int nb_label  = (n_label + 3) / 4;

    hipMemsetAsync(cnt, 0, (size_t)n_nodes * sizeof(int), stream);
    k_count<<<(n_edges + 255) / 256, 256, 0, stream>>>(ei, n_edges, cnt);

    // layer 0: node linear
    k_lin<<<nb_nodes, 256, 0, stream>>>(x, W_lin, b_lin, hA, n_nodes);

    // conv1
    hipMemsetAsync(sum, 0, hbytes, stream);
    k_agg<<<nb_edge64, 256, 0, stream>>>(hA, ei, n_edges, sum);
    k_conv<<<nb_nodes, 256, 0, stream>>>(sum, cnt, hA, Wl1, bl1, Wr1, hB, n_nodes, 1);

    // conv2
    hipMemsetAsync(sum, 0, hbytes, stream);
    k_agg<<<nb_edge64, 256, 0, stream>>>(hB, ei, n_edges, sum);
    k_conv<<<nb_nodes, 256, 0, stream>>>(sum, cnt, hB, Wl2, bl2, Wr2, hA, n_nodes, 0);

    // edge classifier
    k_pred<<<nb_label, 256, 0, stream>>>(hA, eli, n_label, out);
}

// Round 2
// 582.661 us; speedup vs baseline: 2.5561x; 2.5561x over previous
//
#include <hip/hip_runtime.h>

#define DD 64
#define SCAN_CHUNK 1024

// ---------------- count in-degree ----------------
__global__ void k_count(const int* __restrict__ ei, int n_edges, int* __restrict__ cnt) {
    int e = blockIdx.x * blockDim.x + threadIdx.x;
    if (e < n_edges) atomicAdd(&cnt[ei[n_edges + e]], 1);
}

// ---------------- 3-phase exclusive scan over cnt -> row_start ----------------
__global__ void k_scanA(const int* __restrict__ cnt, int n,
                        int* __restrict__ row_start, int* __restrict__ blocksums) {
    __shared__ int lds[256];
    int b = blockIdx.x, t = threadIdx.x;
    int base = b * SCAN_CHUNK + t * 4;
    int v[4]; int s = 0;
    #pragma unroll
    for (int i = 0; i < 4; ++i) { int idx = base + i; v[i] = (idx < n) ? cnt[idx] : 0; s += v[i]; }
    lds[t] = s; __syncthreads();
    for (int off = 1; off < 256; off <<= 1) {
        int x = (t >= off) ? lds[t - off] : 0; __syncthreads();
        lds[t] += x; __syncthreads();
    }
    int run = (t > 0) ? lds[t - 1] : 0;
    if (t == 255) blocksums[b] = lds[255];
    #pragma unroll
    for (int i = 0; i < 4; ++i) { int idx = base + i; if (idx < n) row_start[idx] = run; run += v[i]; }
}

__global__ void k_scanB(int* __restrict__ blocksums, int nb) {
    __shared__ int lds[256];
    int t = threadIdx.x;
    lds[t] = (t < nb) ? blocksums[t] : 0; __syncthreads();
    for (int off = 1; off < 256; off <<= 1) {
        int x = (t >= off) ? lds[t - off] : 0; __syncthreads();
        lds[t] += x; __syncthreads();
    }
    if (t < nb) blocksums[t] = (t > 0) ? lds[t - 1] : 0;
}

__global__ void k_scanC(int* __restrict__ row_start, const int* __restrict__ blocksums,
                        int n, int n_edges) {
    int i = blockIdx.x * 256 + threadIdx.x;
    if (i < n) row_start[i] += blocksums[i / SCAN_CHUNK];
    else if (i == n) row_start[n] = n_edges;
}

// ---------------- scatter edges into CSR ----------------
__global__ void k_scatter(const int* __restrict__ ei, int n_edges,
                          const int* __restrict__ row_start, int* __restrict__ fill,
                          int* __restrict__ csr) {
    int e = blockIdx.x * 256 + threadIdx.x;
    if (e < n_edges) {
        int dst = ei[n_edges + e];
        int pos = row_start[dst] + atomicAdd(&fill[dst], 1);
        csr[pos] = ei[e];
    }
}

// ---------------- gather-mean aggregation: one wave per node ----------------
__global__ void k_gather(const float* __restrict__ h, const int* __restrict__ row_start,
                         const int* __restrict__ csr, float* __restrict__ mean, int n_nodes) {
    int t = threadIdx.x;
    int wv = __builtin_amdgcn_readfirstlane(t >> 6);
    int d = t & 63;
    int n = blockIdx.x * 4 + wv;
    if (n >= n_nodes) return;
    int beg = row_start[n], end = row_start[n + 1];
    float a0 = 0.0f, a1 = 0.0f;
    int j = beg;
    for (; j + 1 < end; j += 2) {
        int s0 = csr[j], s1 = csr[j + 1];
        a0 += h[(size_t)s0 * DD + d];
        a1 += h[(size_t)s1 * DD + d];
    }
    if (j < end) a0 += h[(size_t)csr[j] * DD + d];
    int deg = end - beg;
    float inv = (deg > 0) ? 1.0f / (float)deg : 0.0f;
    mean[(size_t)n * DD + d] = (a0 + a1) * inv;
}

// ------- out = [relu]( A1 @ W1^T + bias [+ A2 @ W2^T] ) -------
// one wave = 16 nodes; weights in 64 VGPRs; activations via scalar loads
__global__ __launch_bounds__(256) void k_gemm(
    const float* __restrict__ A1, const float* __restrict__ A2,
    const float* __restrict__ W1, const float* __restrict__ W2,
    const float* __restrict__ bias, float* __restrict__ out,
    int n_nodes, int relu) {
    __shared__ float Wt[2 * DD * DD];   // Wt[k*64+d] = W[d*64+k]
    int t = threadIdx.x;
    for (int i = t; i < DD * DD; i += 256) Wt[(i & 63) * DD + (i >> 6)] = W1[i];
    if (A2) for (int i = t; i < DD * DD; i += 256) Wt[DD * DD + (i & 63) * DD + (i >> 6)] = W2[i];
    __syncthreads();

    int wv = __builtin_amdgcn_readfirstlane(t >> 6);
    int d = t & 63;
    int n0 = blockIdx.x * 64 + wv * 16;
    if (n0 >= n_nodes) return;
    int m = n_nodes - n0; if (m > 16) m = 16;

    float acc[16];
    float bd = bias[d];
    #pragma unroll
    for (int i = 0; i < 16; ++i) acc[i] = bd;

    float wreg[DD];
    #pragma unroll
    for (int k = 0; k < DD; ++k) wreg[k] = Wt[k * DD + d];

    if (m == 16) {
        #pragma unroll
        for (int i = 0; i < 16; ++i) {
            const float* a = A1 + (size_t)(n0 + i) * DD;
            #pragma unroll
            for (int k = 0; k < DD; ++k) acc[i] += a[k] * wreg[k];
        }
        if (A2) {
            #pragma unroll
            for (int k = 0; k < DD; ++k) wreg[k] = Wt[DD * DD + k * DD + d];
            #pragma unroll
            for (int i = 0; i < 16; ++i) {
                const float* a = A2 + (size_t)(n0 + i) * DD;
                #pragma unroll
                for (int k = 0; k < DD; ++k) acc[i] += a[k] * wreg[k];
            }
        }
    } else {
        for (int i = 0; i < m; ++i) {
            const float* a = A1 + (size_t)(n0 + i) * DD;
            for (int k = 0; k < DD; ++k) acc[i] += a[k] * wreg[k];
        }
        if (A2) {
            #pragma unroll
            for (int k = 0; k < DD; ++k) wreg[k] = Wt[DD * DD + k * DD + d];
            for (int i = 0; i < m; ++i) {
                const float* a = A2 + (size_t)(n0 + i) * DD;
                for (int k = 0; k < DD; ++k) acc[i] += a[k] * wreg[k];
            }
        }
    }

    for (int i = 0; i < 16; ++i) {
        if (i < m) {
            float v = acc[i];
            if (relu) v = fmaxf(v, 0.0f);
            out[(size_t)(n0 + i) * DD + d] = v;
        }
    }
}

// ---------------- preds[e] = dot(h[a], h[b]); one wave per label edge ----------------
__global__ void k_pred(const float* __restrict__ h, const int* __restrict__ eli,
                       int n_label, float* __restrict__ out) {
    int t = threadIdx.x;
    int g = t >> 6, d = t & 63;
    int e = blockIdx.x * 4 + g;
    if (e >= n_label) return;
    int a = eli[e];
    int b = eli[n_label + e];
    float v = h[(size_t)a * DD + d] * h[(size_t)b * DD + d];
    #pragma unroll
    for (int o = 32; o > 0; o >>= 1) v += __shfl_down(v, o, 64);
    if (d == 0) out[e] = v;
}

extern "C" void kernel_launch(void* const* d_in, const int* in_sizes, int n_in,
                              void* d_out, int out_size, void* d_ws, size_t ws_size,
                              hipStream_t stream) {
    const float* x     = (const float*)d_in[0];
    const int*   ei    = (const int*)d_in[1];
    const int*   eli   = (const int*)d_in[2];
    const float* W_lin = (const float*)d_in[3];
    const float* b_lin = (const float*)d_in[4];
    const float* Wl1   = (const float*)d_in[5];
    const float* bl1   = (const float*)d_in[6];
    const float* Wr1   = (const float*)d_in[7];
    const float* Wl2   = (const float*)d_in[8];
    const float* bl2   = (const float*)d_in[9];
    const float* Wr2   = (const float*)d_in[10];

    int n_nodes = in_sizes[0] / DD;
    int n_edges = in_sizes[1] / 2;
    int n_label = in_sizes[2] / 2;
    float* out = (float*)d_out;

    char* ws = (char*)d_ws;
    size_t hbytes = (size_t)n_nodes * DD * sizeof(float);
    float* mean = (float*)ws; ws += hbytes;
    float* hA   = (float*)ws; ws += hbytes;
    float* hB   = (float*)ws; ws += hbytes;
    int* cnt       = (int*)ws; ws += (size_t)((n_nodes + 3) & ~3) * sizeof(int);
    int* fill      = (int*)ws; ws += (size_t)((n_nodes + 3) & ~3) * sizeof(int);
    int* row_start = (int*)ws; ws += (size_t)((n_nodes + 5) & ~3) * sizeof(int);
    int* blocksums = (int*)ws; ws += 256 * sizeof(int);
    int* csr       = (int*)ws; ws += (size_t)n_edges * sizeof(int);

    int nbA = (n_nodes + SCAN_CHUNK - 1) / SCAN_CHUNK;   // 98

    hipMemsetAsync(cnt, 0, (size_t)n_nodes * sizeof(int), stream);
    hipMemsetAsync(fill, 0, (size_t)n_nodes * sizeof(int), stream);

    // CSR build
    k_count<<<(n_edges + 255) / 256, 256, 0, stream>>>(ei, n_edges, cnt);
    k_scanA<<<nbA, 256, 0, stream>>>(cnt, n_nodes, row_start, blocksums);
    k_scanB<<<1, 256, 0, stream>>>(blocksums, nbA);
    k_scanC<<<(n_nodes + 1 + 255) / 256, 256, 0, stream>>>(row_start, blocksums, n_nodes, n_edges);
    k_scatter<<<(n_edges + 255) / 256, 256, 0, stream>>>(ei, n_edges, row_start, fill, csr);

    int nb_gemm   = (n_nodes + 63) / 64;
    int nb_gather = (n_nodes + 3) / 4;
    int nb_label  = (n_label + 3) / 4;

    // layer 0: node linear
    k_gemm<<<nb_gemm, 256, 0, stream>>>(x, nullptr, W_lin, nullptr, b_lin, hA, n_nodes, 0);

    // conv1
    k_gather<<<nb_gather, 256, 0, stream>>>(hA, row_start, csr, mean, n_nodes);
    k_gemm<<<nb_gemm, 256, 0, stream>>>(mean, hA, Wl1, Wr1, bl1, hB, n_nodes, 1);

    // conv2
    k_gather<<<nb_gather, 256, 0, stream>>>(hB, row_start, csr, mean, n_nodes);
    k_gemm<<<nb_gemm, 256, 0, stream>>>(mean, hB, Wl2, Wr2, bl2, hA, n_nodes, 0);

    // edge classifier
    k_pred<<<nb_label, 256, 0, stream>>>(hA, eli, n_label, out);
}

// Round 3
// 432.347 us; speedup vs baseline: 3.4448x; 1.3477x over previous
//
#include <hip/hip_runtime.h>

#define DD 64
#define ROW 65
#define SCAN_CHUNK 1024

// ---------------- count in-degree ----------------
__global__ void k_count(const int* __restrict__ ei, int n_edges, int* __restrict__ cnt) {
    int e = blockIdx.x * blockDim.x + threadIdx.x;
    if (e < n_edges) atomicAdd(&cnt[ei[n_edges + e]], 1);
}

// ---------------- 3-phase exclusive scan over cnt -> row_start ----------------
__global__ void k_scanA(const int* __restrict__ cnt, int n,
                        int* __restrict__ row_start, int* __restrict__ blocksums) {
    __shared__ int lds[256];
    int b = blockIdx.x, t = threadIdx.x;
    int base = b * SCAN_CHUNK + t * 4;
    int v[4]; int s = 0;
    #pragma unroll
    for (int i = 0; i < 4; ++i) { int idx = base + i; v[i] = (idx < n) ? cnt[idx] : 0; s += v[i]; }
    lds[t] = s; __syncthreads();
    for (int off = 1; off < 256; off <<= 1) {
        int x = (t >= off) ? lds[t - off] : 0; __syncthreads();
        lds[t] += x; __syncthreads();
    }
    int run = (t > 0) ? lds[t - 1] : 0;
    if (t == 255) blocksums[b] = lds[255];
    #pragma unroll
    for (int i = 0; i < 4; ++i) { int idx = base + i; if (idx < n) row_start[idx] = run; run += v[i]; }
}

__global__ void k_scanB(int* __restrict__ blocksums, int nb) {
    __shared__ int lds[256];
    int t = threadIdx.x;
    lds[t] = (t < nb) ? blocksums[t] : 0; __syncthreads();
    for (int off = 1; off < 256; off <<= 1) {
        int x = (t >= off) ? lds[t - off] : 0; __syncthreads();
        lds[t] += x; __syncthreads();
    }
    if (t < nb) blocksums[t] = (t > 0) ? lds[t - 1] : 0;
}

__global__ void k_scanC(int* __restrict__ row_start, const int* __restrict__ blocksums,
                        int n, int n_edges) {
    int i = blockIdx.x * 256 + threadIdx.x;
    if (i < n) row_start[i] += blocksums[i / SCAN_CHUNK];
    else if (i == n) row_start[n] = n_edges;
}

// ---------------- scatter edges into CSR ----------------
__global__ void k_scatter(const int* __restrict__ ei, int n_edges,
                          const int* __restrict__ row_start, int* __restrict__ fill,
                          int* __restrict__ csr) {
    int e = blockIdx.x * 256 + threadIdx.x;
    if (e < n_edges) {
        int dst = ei[n_edges + e];
        int pos = row_start[dst] + atomicAdd(&fill[dst], 1);
        csr[pos] = ei[e];
    }
}

// ---------------- gather-mean: one wave per node, float4 lanes ----------------
// lane = 16*q + r : q = neighbor slot (0..3), r = dim quad (0..15)
__global__ void k_gather(const float* __restrict__ h, const int* __restrict__ row_start,
                         const int* __restrict__ csr, float* __restrict__ mean, int n_nodes) {
    int t = threadIdx.x;
    int l = t & 63;
    int r = l & 15;
    int q = l >> 4;
    int n = blockIdx.x * 4 + (t >> 6);
    if (n >= n_nodes) return;
    int beg = row_start[n], end = row_start[n + 1];
    float ax = 0.f, ay = 0.f, az = 0.f, aw = 0.f;
    for (int j = beg; j < end; j += 4) {
        int jj = j + q;
        if (jj < end) {
            int s = csr[jj];
            float4 v = *(const float4*)(h + (size_t)s * DD + r * 4);
            ax += v.x; ay += v.y; az += v.z; aw += v.w;
        }
    }
    // sum across the 4 q-slots
    ax += __shfl_xor(ax, 16, 64); ay += __shfl_xor(ay, 16, 64);
    az += __shfl_xor(az, 16, 64); aw += __shfl_xor(aw, 16, 64);
    ax += __shfl_xor(ax, 32, 64); ay += __shfl_xor(ay, 32, 64);
    az += __shfl_xor(az, 32, 64); aw += __shfl_xor(aw, 32, 64);
    int deg = end - beg;
    float inv = (deg > 0) ? 1.0f / (float)deg : 0.0f;
    if (q == 0) {
        float4 o; o.x = ax * inv; o.y = ay * inv; o.z = az * inv; o.w = aw * inv;
        *(float4*)(mean + (size_t)n * DD + r * 4) = o;
    }
}

// ------- out = [relu]( A1 @ W1^T + bias [+ A2 @ W2^T] ) -------
// 256 threads, 64 nodes/block; thread tile = 4 nodes x 4 dims.
// All LDS arrays are padded direct copies [64][ROW]; b32 reads, broadcast-heavy.
__global__ __launch_bounds__(256) void k_gemm(
    const float* __restrict__ A1, const float* __restrict__ A2,
    const float* __restrict__ W1, const float* __restrict__ W2,
    const float* __restrict__ bias, float* __restrict__ out,
    int n_nodes, int relu) {
    __shared__ float As1[DD * ROW];
    __shared__ float Ws1[DD * ROW];
    __shared__ float As2[DD * ROW];
    __shared__ float Ws2[DD * ROW];

    int t = threadIdx.x;
    int tx = t & 15, ty = t >> 4;
    int n_base = blockIdx.x * DD;

    // stage weights: Ws[d][k] = W[d*64+k]  (b32 stores, conflict-free via ROW=65)
    {
        int idx = t * 4;
        #pragma unroll
        for (int it = 0; it < 4; ++it, idx += 1024) {
            int d = idx >> 6, k0 = idx & 63;
            float4 w = *(const float4*)(W1 + idx);
            float* p = Ws1 + d * ROW + k0;
            p[0] = w.x; p[1] = w.y; p[2] = w.z; p[3] = w.w;
            if (A2) {
                float4 u = *(const float4*)(W2 + idx);
                float* p2 = Ws2 + d * ROW + k0;
                p2[0] = u.x; p2[1] = u.y; p2[2] = u.z; p2[3] = u.w;
            }
        }
    }
    // stage activations: As[n][k] = A[(n_base+n)*64 + k]
    {
        int k0 = tx * 4;
        #pragma unroll
        for (int it = 0; it < 4; ++it) {
            int n = it * 16 + ty;
            int gn = n_base + n;
            float4 a;
            if (gn < n_nodes) a = *(const float4*)(A1 + (size_t)gn * DD + k0);
            else { a.x = 0.f; a.y = 0.f; a.z = 0.f; a.w = 0.f; }
            float* p = As1 + n * ROW + k0;
            p[0] = a.x; p[1] = a.y; p[2] = a.z; p[3] = a.w;
            if (A2) {
                float4 c;
                if (gn < n_nodes) c = *(const float4*)(A2 + (size_t)gn * DD + k0);
                else { c.x = 0.f; c.y = 0.f; c.z = 0.f; c.w = 0.f; }
                float* p2 = As2 + n * ROW + k0;
                p2[0] = c.x; p2[1] = c.y; p2[2] = c.z; p2[3] = c.w;
            }
        }
    }
    __syncthreads();

    float acc[4][4];
    #pragma unroll
    for (int j = 0; j < 4; ++j) {
        float bj = bias[tx * 4 + j];
        #pragma unroll
        for (int i = 0; i < 4; ++i) acc[i][j] = bj;
    }

    const float* a_row = As1 + (ty * 4) * ROW;
    const float* w_row = Ws1 + (tx * 4) * ROW;
    #pragma unroll 8
    for (int k = 0; k < DD; ++k) {
        float av[4], wv[4];
        #pragma unroll
        for (int i = 0; i < 4; ++i) av[i] = a_row[i * ROW + k];
        #pragma unroll
        for (int j = 0; j < 4; ++j) wv[j] = w_row[j * ROW + k];
        #pragma unroll
        for (int i = 0; i < 4; ++i)
            #pragma unroll
            for (int j = 0; j < 4; ++j) acc[i][j] += av[i] * wv[j];
    }
    if (A2) {
        const float* a2_row = As2 + (ty * 4) * ROW;
        const float* w2_row = Ws2 + (tx * 4) * ROW;
        #pragma unroll 8
        for (int k = 0; k < DD; ++k) {
            float av[4], wv[4];
            #pragma unroll
            for (int i = 0; i < 4; ++i) av[i] = a2_row[i * ROW + k];
            #pragma unroll
            for (int j = 0; j < 4; ++j) wv[j] = w2_row[j * ROW + k];
            #pragma unroll
            for (int i = 0; i < 4; ++i)
                #pragma unroll
                for (int j = 0; j < 4; ++j) acc[i][j] += av[i] * wv[j];
        }
    }

    #pragma unroll
    for (int i = 0; i < 4; ++i) {
        int n = n_base + ty * 4 + i;
        if (n < n_nodes) {
            float4 o;
            o.x = acc[i][0]; o.y = acc[i][1]; o.z = acc[i][2]; o.w = acc[i][3];
            if (relu) {
                o.x = fmaxf(o.x, 0.f); o.y = fmaxf(o.y, 0.f);
                o.z = fmaxf(o.z, 0.f); o.w = fmaxf(o.w, 0.f);
            }
            *(float4*)(out + (size_t)n * DD + tx * 4) = o;
        }
    }
}

// ---------------- preds: 2 edges per wave, float4 + shfl_xor dot ----------------
__global__ void k_pred(const float* __restrict__ h, const int* __restrict__ eli,
                       int n_label, float* __restrict__ out) {
    int t = threadIdx.x;
    int e = blockIdx.x * 8 + (t >> 5);
    if (e >= n_label) return;
    int g = (t >> 4) & 1;
    int r = t & 15;
    int node = g ? eli[n_label + e] : eli[e];
    float4 v = *(const float4*)(h + (size_t)node * DD + r * 4);
    float wx = __shfl_xor(v.x, 16, 64);
    float wy = __shfl_xor(v.y, 16, 64);
    float wz = __shfl_xor(v.z, 16, 64);
    float ww = __shfl_xor(v.w, 16, 64);
    float s = v.x * wx + v.y * wy + v.z * wz + v.w * ww;
    #pragma unroll
    for (int off = 1; off < 16; off <<= 1) s += __shfl_xor(s, off, 64);
    if ((t & 31) == 0) out[e] = s;
}

extern "C" void kernel_launch(void* const* d_in, const int* in_sizes, int n_in,
                              void* d_out, int out_size, void* d_ws, size_t ws_size,
                              hipStream_t stream) {
    const float* x     = (const float*)d_in[0];
    const int*   ei    = (const int*)d_in[1];
    const int*   eli   = (const int*)d_in[2];
    const float* W_lin = (const float*)d_in[3];
    const float* b_lin = (const float*)d_in[4];
    const float* Wl1   = (const float*)d_in[5];
    const float* bl1   = (const float*)d_in[6];
    const float* Wr1   = (const float*)d_in[7];
    const float* Wl2   = (const float*)d_in[8];
    const float* bl2   = (const float*)d_in[9];
    const float* Wr2   = (const float*)d_in[10];

    int n_nodes = in_sizes[0] / DD;
    int n_edges = in_sizes[1] / 2;
    int n_label = in_sizes[2] / 2;
    float* out = (float*)d_out;

    char* ws = (char*)d_ws;
    size_t hbytes = (size_t)n_nodes * DD * sizeof(float);
    float* mean = (float*)ws; ws += hbytes;
    float* hA   = (float*)ws; ws += hbytes;
    float* hB   = (float*)ws; ws += hbytes;
    int* cnt       = (int*)ws; ws += (size_t)((n_nodes + 3) & ~3) * sizeof(int);
    int* fill      = (int*)ws; ws += (size_t)((n_nodes + 3) & ~3) * sizeof(int);
    int* row_start = (int*)ws; ws += (size_t)((n_nodes + 5) & ~3) * sizeof(int);
    int* blocksums = (int*)ws; ws += 256 * sizeof(int);
    int* csr       = (int*)ws; ws += (size_t)n_edges * sizeof(int);

    int nbA = (n_nodes + SCAN_CHUNK - 1) / SCAN_CHUNK;

    hipMemsetAsync(cnt, 0, (size_t)n_nodes * sizeof(int), stream);
    hipMemsetAsync(fill, 0, (size_t)n_nodes * sizeof(int), stream);

    // CSR build
    k_count<<<(n_edges + 255) / 256, 256, 0, stream>>>(ei, n_edges, cnt);
    k_scanA<<<nbA, 256, 0, stream>>>(cnt, n_nodes, row_start, blocksums);
    k_scanB<<<1, 256, 0, stream>>>(blocksums, nbA);
    k_scanC<<<(n_nodes + 1 + 255) / 256, 256, 0, stream>>>(row_start, blocksums, n_nodes, n_edges);
    k_scatter<<<(n_edges + 255) / 256, 256, 0, stream>>>(ei, n_edges, row_start, fill, csr);

    int nb_gemm   = (n_nodes + DD - 1) / DD;
    int nb_gather = (n_nodes + 3) / 4;
    int nb_pred   = (n_label + 7) / 8;

    // layer 0: node linear
    k_gemm<<<nb_gemm, 256, 0, stream>>>(x, nullptr, W_lin, nullptr, b_lin, hA, n_nodes, 0);

    // conv1
    k_gather<<<nb_gather, 256, 0, stream>>>(hA, row_start, csr, mean, n_nodes);
    k_gemm<<<nb_gemm, 256, 0, stream>>>(mean, hA, Wl1, Wr1, bl1, hB, n_nodes, 1);

    // conv2
    k_gather<<<nb_gather, 256, 0, stream>>>(hB, row_start, csr, mean, n_nodes);
    k_gemm<<<nb_gemm, 256, 0, stream>>>(mean, hB, Wl2, Wr2, bl2, hA, n_nodes, 0);

    // edge classifier
    k_pred<<<nb_pred, 256, 0, stream>>>(hA, eli, n_label, out);
}

// Round 4
// 400.233 us; speedup vs baseline: 3.7212x; 1.0802x over previous
//
#include <hip/hip_runtime.h>

#define DD 64
#define ROW 65
#define SCAN_CHUNK 1024

typedef unsigned short u16;
typedef u16 ushort4v __attribute__((ext_vector_type(4)));
typedef u16 ushort8v __attribute__((ext_vector_type(8)));

__device__ __forceinline__ float bf2f(u16 u) {
    union { unsigned u32; float f; } x; x.u32 = (unsigned)u << 16; return x.f;
}
__device__ __forceinline__ u16 f2bf(float f) {
    union { float f; unsigned u; } x; x.f = f;
    unsigned r = (x.u + 0x7fffu + ((x.u >> 16) & 1u)) >> 16;   // RTNE
    return (u16)r;
}

// ---------------- count in-degree ----------------
__global__ void k_count(const int* __restrict__ ei, int n_edges, int* __restrict__ cnt) {
    int e = blockIdx.x * blockDim.x + threadIdx.x;
    if (e < n_edges) atomicAdd(&cnt[ei[n_edges + e]], 1);
}

// ---------------- 3-phase exclusive scan over cnt -> row_start ----------------
__global__ void k_scanA(const int* __restrict__ cnt, int n,
                        int* __restrict__ row_start, int* __restrict__ blocksums) {
    __shared__ int lds[256];
    int b = blockIdx.x, t = threadIdx.x;
    int base = b * SCAN_CHUNK + t * 4;
    int v[4]; int s = 0;
    #pragma unroll
    for (int i = 0; i < 4; ++i) { int idx = base + i; v[i] = (idx < n) ? cnt[idx] : 0; s += v[i]; }
    lds[t] = s; __syncthreads();
    for (int off = 1; off < 256; off <<= 1) {
        int x = (t >= off) ? lds[t - off] : 0; __syncthreads();
        lds[t] += x; __syncthreads();
    }
    int run = (t > 0) ? lds[t - 1] : 0;
    if (t == 255) blocksums[b] = lds[255];
    #pragma unroll
    for (int i = 0; i < 4; ++i) { int idx = base + i; if (idx < n) row_start[idx] = run; run += v[i]; }
}

__global__ void k_scanB(int* __restrict__ blocksums, int nb) {
    __shared__ int lds[256];
    int t = threadIdx.x;
    lds[t] = (t < nb) ? blocksums[t] : 0; __syncthreads();
    for (int off = 1; off < 256; off <<= 1) {
        int x = (t >= off) ? lds[t - off] : 0; __syncthreads();
        lds[t] += x; __syncthreads();
    }
    if (t < nb) blocksums[t] = (t > 0) ? lds[t - 1] : 0;
}

__global__ void k_scanC(int* __restrict__ row_start, const int* __restrict__ blocksums,
                        int n, int n_edges) {
    int i = blockIdx.x * 256 + threadIdx.x;
    if (i < n) row_start[i] += blocksums[i / SCAN_CHUNK];
    else if (i == n) row_start[n] = n_edges;
}

// ---------------- scatter edges into CSR ----------------
__global__ void k_scatter(const int* __restrict__ ei, int n_edges,
                          const int* __restrict__ row_start, int* __restrict__ fill,
                          int* __restrict__ csr) {
    int e = blockIdx.x * 256 + threadIdx.x;
    if (e < n_edges) {
        int dst = ei[n_edges + e];
        int pos = row_start[dst] + atomicAdd(&fill[dst], 1);
        csr[pos] = ei[e];
    }
}

// ---------------- gather-mean: one wave per node, bf16 rows (128 B) ----------------
// lane = 8*q + r : q = neighbor slot (0..7), r = dim octet (0..7), ushort8 loads
__global__ void k_gather(const u16* __restrict__ h, const int* __restrict__ row_start,
                         const int* __restrict__ csr, u16* __restrict__ mean, int n_nodes) {
    int t = threadIdx.x;
    int l = t & 63;
    int r = l & 7;
    int q = l >> 3;
    int n = blockIdx.x * 4 + (t >> 6);
    if (n >= n_nodes) return;
    int beg = row_start[n], end = row_start[n + 1];
    float a[8];
    #pragma unroll
    for (int i = 0; i < 8; ++i) a[i] = 0.f;
    for (int j = beg + q; j < end; j += 8) {
        int s = csr[j];
        ushort8v v = *(const ushort8v*)(h + (size_t)s * DD + r * 8);
        #pragma unroll
        for (int i = 0; i < 8; ++i) a[i] += bf2f(v[i]);
    }
    #pragma unroll
    for (int off = 8; off < 64; off <<= 1) {
        #pragma unroll
        for (int i = 0; i < 8; ++i) a[i] += __shfl_xor(a[i], off, 64);
    }
    int deg = end - beg;
    float inv = (deg > 0) ? 1.0f / (float)deg : 0.0f;
    if (q == 0) {
        ushort8v o;
        #pragma unroll
        for (int i = 0; i < 8; ++i) o[i] = f2bf(a[i] * inv);
        *(ushort8v*)(mean + (size_t)n * DD + r * 8) = o;
    }
}

// ------- out(bf16) = [relu]( A1 @ W1^T + bias [+ A2 @ W2^T] ) -------
// 256 threads, 64 nodes/block; thread tile = 4 nodes x 4 dims; fp32 math in LDS.
template <typename T>
__global__ __launch_bounds__(256) void k_gemm(
    const T* __restrict__ A1, const T* __restrict__ A2,
    const float* __restrict__ W1, const float* __restrict__ W2,
    const float* __restrict__ bias, u16* __restrict__ out,
    int n_nodes, int relu) {
    __shared__ float As1[DD * ROW];
    __shared__ float Ws1[DD * ROW];
    __shared__ float As2[DD * ROW];
    __shared__ float Ws2[DD * ROW];

    int t = threadIdx.x;
    int tx = t & 15, ty = t >> 4;
    int n_base = blockIdx.x * DD;

    // stage weights: Ws[d][k] = W[d*64+k]
    {
        int idx = t * 4;
        #pragma unroll
        for (int it = 0; it < 4; ++it, idx += 1024) {
            int d = idx >> 6, k0 = idx & 63;
            float4 w = *(const float4*)(W1 + idx);
            float* p = Ws1 + d * ROW + k0;
            p[0] = w.x; p[1] = w.y; p[2] = w.z; p[3] = w.w;
            if (A2) {
                float4 u = *(const float4*)(W2 + idx);
                float* p2 = Ws2 + d * ROW + k0;
                p2[0] = u.x; p2[1] = u.y; p2[2] = u.z; p2[3] = u.w;
            }
        }
    }
    // stage activations: As[n][k] (convert to fp32 if bf16)
    for (int i = t; i < 1024; i += 256) {
        int n = i >> 4, k0 = (i & 15) * 4;
        int gn = n_base + n;
        float va[4] = {0.f, 0.f, 0.f, 0.f};
        if (gn < n_nodes) {
            if constexpr (sizeof(T) == 2) {
                ushort4v v = *(const ushort4v*)(A1 + (size_t)gn * DD + k0);
                #pragma unroll
                for (int j = 0; j < 4; ++j) va[j] = bf2f(v[j]);
            } else {
                float4 v = *(const float4*)(A1 + (size_t)gn * DD + k0);
                va[0] = v.x; va[1] = v.y; va[2] = v.z; va[3] = v.w;
            }
        }
        float* p = As1 + n * ROW + k0;
        p[0] = va[0]; p[1] = va[1]; p[2] = va[2]; p[3] = va[3];
        if (A2) {
            float vc[4] = {0.f, 0.f, 0.f, 0.f};
            if (gn < n_nodes) {
                if constexpr (sizeof(T) == 2) {
                    ushort4v v = *(const ushort4v*)(A2 + (size_t)gn * DD + k0);
                    #pragma unroll
                    for (int j = 0; j < 4; ++j) vc[j] = bf2f(v[j]);
                } else {
                    float4 v = *(const float4*)(A2 + (size_t)gn * DD + k0);
                    vc[0] = v.x; vc[1] = v.y; vc[2] = v.z; vc[3] = v.w;
                }
            }
            float* p2 = As2 + n * ROW + k0;
            p2[0] = vc[0]; p2[1] = vc[1]; p2[2] = vc[2]; p2[3] = vc[3];
        }
    }
    __syncthreads();

    float acc[4][4];
    #pragma unroll
    for (int j = 0; j < 4; ++j) {
        float bj = bias[tx * 4 + j];
        #pragma unroll
        for (int i = 0; i < 4; ++i) acc[i][j] = bj;
    }

    const float* a_row = As1 + (ty * 4) * ROW;
    const float* w_row = Ws1 + (tx * 4) * ROW;
    #pragma unroll 8
    for (int k = 0; k < DD; ++k) {
        float av[4], wv[4];
        #pragma unroll
        for (int i = 0; i < 4; ++i) av[i] = a_row[i * ROW + k];
        #pragma unroll
        for (int j = 0; j < 4; ++j) wv[j] = w_row[j * ROW + k];
        #pragma unroll
        for (int i = 0; i < 4; ++i)
            #pragma unroll
            for (int j = 0; j < 4; ++j) acc[i][j] += av[i] * wv[j];
    }
    if (A2) {
        const float* a2_row = As2 + (ty * 4) * ROW;
        const float* w2_row = Ws2 + (tx * 4) * ROW;
        #pragma unroll 8
        for (int k = 0; k < DD; ++k) {
            float av[4], wv[4];
            #pragma unroll
            for (int i = 0; i < 4; ++i) av[i] = a2_row[i * ROW + k];
            #pragma unroll
            for (int j = 0; j < 4; ++j) wv[j] = w2_row[j * ROW + k];
            #pragma unroll
            for (int i = 0; i < 4; ++i)
                #pragma unroll
                for (int j = 0; j < 4; ++j) acc[i][j] += av[i] * wv[j];
        }
    }

    #pragma unroll
    for (int i = 0; i < 4; ++i) {
        int n = n_base + ty * 4 + i;
        if (n < n_nodes) {
            float v0 = acc[i][0], v1 = acc[i][1], v2 = acc[i][2], v3 = acc[i][3];
            if (relu) {
                v0 = fmaxf(v0, 0.f); v1 = fmaxf(v1, 0.f);
                v2 = fmaxf(v2, 0.f); v3 = fmaxf(v3, 0.f);
            }
            ushort4v o;
            o[0] = f2bf(v0); o[1] = f2bf(v1); o[2] = f2bf(v2); o[3] = f2bf(v3);
            *(ushort4v*)(out + (size_t)n * DD + tx * 4) = o;
        }
    }
}

// ---------------- preds: 2 edges per wave, bf16 rows ----------------
__global__ void k_pred(const u16* __restrict__ h, const int* __restrict__ eli,
                       int n_label, float* __restrict__ out) {
    int t = threadIdx.x;
    int e = blockIdx.x * 8 + (t >> 5);
    if (e >= n_label) return;
    int g = (t >> 4) & 1;
    int r = t & 15;
    int node = g ? eli[n_label + e] : eli[e];
    ushort4v v = *(const ushort4v*)(h + (size_t)node * DD + r * 4);
    float f0 = bf2f(v[0]), f1 = bf2f(v[1]), f2 = bf2f(v[2]), f3 = bf2f(v[3]);
    float w0 = __shfl_xor(f0, 16, 64);
    float w1 = __shfl_xor(f1, 16, 64);
    float w2 = __shfl_xor(f2, 16, 64);
    float w3 = __shfl_xor(f3, 16, 64);
    float s = f0 * w0 + f1 * w1 + f2 * w2 + f3 * w3;
    #pragma unroll
    for (int off = 1; off < 16; off <<= 1) s += __shfl_xor(s, off, 64);
    if ((t & 31) == 0) out[e] = s;
}

extern "C" void kernel_launch(void* const* d_in, const int* in_sizes, int n_in,
                              void* d_out, int out_size, void* d_ws, size_t ws_size,
                              hipStream_t stream) {
    const float* x     = (const float*)d_in[0];
    const int*   ei    = (const int*)d_in[1];
    const int*   eli   = (const int*)d_in[2];
    const float* W_lin = (const float*)d_in[3];
    const float* b_lin = (const float*)d_in[4];
    const float* Wl1   = (const float*)d_in[5];
    const float* bl1   = (const float*)d_in[6];
    const float* Wr1   = (const float*)d_in[7];
    const float* Wl2   = (const float*)d_in[8];
    const float* bl2   = (const float*)d_in[9];
    const float* Wr2   = (const float*)d_in[10];

    int n_nodes = in_sizes[0] / DD;
    int n_edges = in_sizes[1] / 2;
    int n_label = in_sizes[2] / 2;
    float* out = (float*)d_out;

    char* ws = (char*)d_ws;
    size_t hbytes = (size_t)n_nodes * DD * sizeof(u16);
    u16* mean = (u16*)ws; ws += hbytes;
    u16* hA   = (u16*)ws; ws += hbytes;
    u16* hB   = (u16*)ws; ws += hbytes;
    int* cnt       = (int*)ws; ws += (size_t)((n_nodes + 3) & ~3) * sizeof(int);
    int* fill      = (int*)ws; ws += (size_t)((n_nodes + 3) & ~3) * sizeof(int);
    int* row_start = (int*)ws; ws += (size_t)((n_nodes + 5) & ~3) * sizeof(int);
    int* blocksums = (int*)ws; ws += 256 * sizeof(int);
    int* csr       = (int*)ws; ws += (size_t)n_edges * sizeof(int);

    int nbA = (n_nodes + SCAN_CHUNK - 1) / SCAN_CHUNK;

    hipMemsetAsync(cnt, 0, (size_t)n_nodes * sizeof(int), stream);
    hipMemsetAsync(fill, 0, (size_t)n_nodes * sizeof(int), stream);

    // CSR build
    k_count<<<(n_edges + 255) / 256, 256, 0, stream>>>(ei, n_edges, cnt);
    k_scanA<<<nbA, 256, 0, stream>>>(cnt, n_nodes, row_start, blocksums);
    k_scanB<<<1, 256, 0, stream>>>(blocksums, nbA);
    k_scanC<<<(n_nodes + 1 + 255) / 256, 256, 0, stream>>>(row_start, blocksums, n_nodes, n_edges);
    k_scatter<<<(n_edges + 255) / 256, 256, 0, stream>>>(ei, n_edges, row_start, fill, csr);

    int nb_gemm   = (n_nodes + DD - 1) / DD;
    int nb_gather = (n_nodes + 3) / 4;
    int nb_pred   = (n_label + 7) / 8;

    // layer 0: node linear (fp32 x -> bf16 h0)
    k_gemm<float><<<nb_gemm, 256, 0, stream>>>(x, nullptr, W_lin, nullptr, b_lin, hA, n_nodes, 0);

    // conv1
    k_gather<<<nb_gather, 256, 0, stream>>>(hA, row_start, csr, mean, n_nodes);
    k_gemm<u16><<<nb_gemm, 256, 0, stream>>>(mean, hA, Wl1, Wr1, bl1, hB, n_nodes, 1);

    // conv2
    k_gather<<<nb_gather, 256, 0, stream>>>(hB, row_start, csr, mean, n_nodes);
    k_gemm<u16><<<nb_gemm, 256, 0, stream>>>(mean, hB, Wl2, Wr2, bl2, hA, n_nodes, 0);

    // edge classifier
    k_pred<<<nb_pred, 256, 0, stream>>>(hA, eli, n_label, out);
}

// Round 5
// 348.108 us; speedup vs baseline: 4.2784x; 1.1497x over previous
//
#include <hip/hip_runtime.h>

#define DD 64
#define ROW 65
#define BW 512            // nodes per bucket (dst >> 9)
#define NBMAX 256         // supports n_nodes <= 131072
#define CAP 8192          // LDS csr staging capacity per bucket
#define CHUNK 2048        // edges per block in hist/part

typedef unsigned short u16;
typedef u16 ushort4v __attribute__((ext_vector_type(4)));
typedef u16 ushort8v __attribute__((ext_vector_type(8)));

__device__ __forceinline__ float bf2f(u16 u) {
    union { unsigned u32; float f; } x; x.u32 = (unsigned)u << 16; return x.f;
}
__device__ __forceinline__ u16 f2bf(float f) {
    union { float f; unsigned u; } x; x.f = f;
    unsigned r = (x.u + 0x7fffu + ((x.u >> 16) & 1u)) >> 16;   // RTNE
    return (u16)r;
}

// ---------------- pass A: bucket histogram ----------------
__global__ void k_hist(const int* __restrict__ ei, int n_edges, int* __restrict__ bucket_cnt) {
    __shared__ int hist[NBMAX];
    int t = threadIdx.x;
    hist[t] = 0;
    __syncthreads();
    int c0 = blockIdx.x * CHUNK;
    int c1 = min(n_edges, c0 + CHUNK);
    for (int e = c0 + t; e < c1; e += 256)
        atomicAdd(&hist[ei[n_edges + e] >> 9], 1);
    __syncthreads();
    if (hist[t] > 0) atomicAdd(&bucket_cnt[t], hist[t]);
}

// ---------------- pass B: scan bucket totals ----------------
__global__ void k_bscan(const int* __restrict__ bucket_cnt, int* __restrict__ cursor,
                        int* __restrict__ bucket_start, int* __restrict__ row_start,
                        int nb, int n_edges, int n_nodes) {
    __shared__ int lds[256];
    int t = threadIdx.x;
    lds[t] = (t < nb) ? bucket_cnt[t] : 0;
    __syncthreads();
    for (int off = 1; off < 256; off <<= 1) {
        int x = (t >= off) ? lds[t - off] : 0;
        __syncthreads();
        if (t >= off) lds[t] += x;
        __syncthreads();
    }
    int excl = (t == 0) ? 0 : lds[t - 1];
    if (t < nb) { bucket_start[t] = excl; cursor[t] = excl; }
    if (t == 0) { bucket_start[nb] = n_edges; row_start[n_nodes] = n_edges; }
}

// ---------------- pass C: partition edges into buckets ----------------
// part[pos] = (src << 9) | (dst & 511)
__global__ void k_part(const int* __restrict__ ei, int n_edges,
                       int* __restrict__ cursor, unsigned* __restrict__ part) {
    __shared__ int hist[NBMAX];
    __shared__ int curs[NBMAX];
    int t = threadIdx.x;
    hist[t] = 0;
    __syncthreads();
    int c0 = blockIdx.x * CHUNK;
    int c1 = min(n_edges, c0 + CHUNK);
    for (int e = c0 + t; e < c1; e += 256)
        atomicAdd(&hist[ei[n_edges + e] >> 9], 1);
    __syncthreads();
    int base = 0;
    if (hist[t] > 0) base = atomicAdd(&cursor[t], hist[t]);
    curs[t] = base;
    __syncthreads();
    for (int e = c0 + t; e < c1; e += 256) {
        int dst = ei[n_edges + e];
        int src = ei[e];
        int b = dst >> 9;
        int pos = atomicAdd(&curs[b], 1);
        part[pos] = ((unsigned)src << 9) | (unsigned)(dst & 511);
    }
}

// ---------------- pass D: per-bucket row_start + csr build in LDS ----------------
__global__ __launch_bounds__(256) void k_build(const unsigned* __restrict__ part,
                        const int* __restrict__ bucket_start,
                        int* __restrict__ row_start, int* __restrict__ csr, int n_nodes) {
    __shared__ int cnt_l[BW];
    __shared__ int sc[BW];
    __shared__ unsigned csr_l[CAP];
    int t = threadIdx.x;
    int b = blockIdx.x;
    int beg = bucket_start[b], end = bucket_start[b + 1];
    int size = end - beg;

    cnt_l[t] = 0; cnt_l[256 + t] = 0;
    __syncthreads();
    // count per local dst
    for (int j = beg + t; j < end; j += 256)
        atomicAdd(&cnt_l[part[j] & 511], 1);
    __syncthreads();
    // inclusive scan of 512 counts (two halves), then zero cnt_l for reuse as fill
    int v0 = cnt_l[t], v1 = cnt_l[256 + t];
    sc[t] = v0; sc[256 + t] = v1;
    cnt_l[t] = 0; cnt_l[256 + t] = 0;
    __syncthreads();
    for (int off = 1; off < 256; off <<= 1) {
        int a = (t >= off) ? sc[t - off] : 0;
        int c = (t >= off) ? sc[256 + t - off] : 0;
        __syncthreads();
        if (t >= off) { sc[t] += a; sc[256 + t] += c; }
        __syncthreads();
    }
    int tot0 = sc[255];
    __syncthreads();
    sc[256 + t] += tot0;
    __syncthreads();
    // write row_start (exclusive prefix + bucket base)
    {
        int n0 = b * BW + t;
        if (n0 < n_nodes) row_start[n0] = beg + ((t == 0) ? 0 : sc[t - 1]);
        int n1 = b * BW + 256 + t;
        if (n1 < n_nodes) row_start[n1] = beg + sc[255 + t];  // excl(256+t) = sc[256+t-1]
    }
    // scatter
    if (size <= CAP) {
        for (int j = beg + t; j < end; j += 256) {
            unsigned p = part[j];
            int dl = (int)(p & 511u);
            int pos = ((dl == 0) ? 0 : sc[dl - 1]) + atomicAdd(&cnt_l[dl], 1);
            csr_l[pos] = p >> 9;
        }
        __syncthreads();
        for (int i = t; i < size; i += 256) csr[beg + i] = (int)csr_l[i];
    } else {
        for (int j = beg + t; j < end; j += 256) {
            unsigned p = part[j];
            int dl = (int)(p & 511u);
            int pos = ((dl == 0) ? 0 : sc[dl - 1]) + atomicAdd(&cnt_l[dl], 1);
            csr[beg + pos] = (int)(p >> 9);
        }
    }
}

// ---------------- gather-mean: one wave per node, bf16 rows (128 B) ----------------
__global__ void k_gather(const u16* __restrict__ h, const int* __restrict__ row_start,
                         const int* __restrict__ csr, u16* __restrict__ mean, int n_nodes) {
    int t = threadIdx.x;
    int l = t & 63;
    int r = l & 7;
    int q = l >> 3;
    int n = blockIdx.x * 4 + (t >> 6);
    if (n >= n_nodes) return;
    int beg = row_start[n], end = row_start[n + 1];
    float a[8];
    #pragma unroll
    for (int i = 0; i < 8; ++i) a[i] = 0.f;
    for (int j = beg + q; j < end; j += 8) {
        int s = csr[j];
        ushort8v v = *(const ushort8v*)(h + (size_t)s * DD + r * 8);
        #pragma unroll
        for (int i = 0; i < 8; ++i) a[i] += bf2f(v[i]);
    }
    #pragma unroll
    for (int off = 8; off < 64; off <<= 1) {
        #pragma unroll
        for (int i = 0; i < 8; ++i) a[i] += __shfl_xor(a[i], off, 64);
    }
    int deg = end - beg;
    float inv = (deg > 0) ? 1.0f / (float)deg : 0.0f;
    if (q == 0) {
        ushort8v o;
        #pragma unroll
        for (int i = 0; i < 8; ++i) o[i] = f2bf(a[i] * inv);
        *(ushort8v*)(mean + (size_t)n * DD + r * 8) = o;
    }
}

// ------- out(bf16) = [relu]( A1 @ W1^T + bias [+ A2 @ W2^T] ) -------
template <typename T>
__global__ __launch_bounds__(256) void k_gemm(
    const T* __restrict__ A1, const T* __restrict__ A2,
    const float* __restrict__ W1, const float* __restrict__ W2,
    const float* __restrict__ bias, u16* __restrict__ out,
    int n_nodes, int relu) {
    __shared__ float As1[DD * ROW];
    __shared__ float Ws1[DD * ROW];
    __shared__ float As2[DD * ROW];
    __shared__ float Ws2[DD * ROW];

    int t = threadIdx.x;
    int tx = t & 15, ty = t >> 4;
    int n_base = blockIdx.x * DD;

    {
        int idx = t * 4;
        #pragma unroll
        for (int it = 0; it < 4; ++it, idx += 1024) {
            int d = idx >> 6, k0 = idx & 63;
            float4 w = *(const float4*)(W1 + idx);
            float* p = Ws1 + d * ROW + k0;
            p[0] = w.x; p[1] = w.y; p[2] = w.z; p[3] = w.w;
            if (A2) {
                float4 u = *(const float4*)(W2 + idx);
                float* p2 = Ws2 + d * ROW + k0;
                p2[0] = u.x; p2[1] = u.y; p2[2] = u.z; p2[3] = u.w;
            }
        }
    }
    for (int i = t; i < 1024; i += 256) {
        int n = i >> 4, k0 = (i & 15) * 4;
        int gn = n_base + n;
        float va[4] = {0.f, 0.f, 0.f, 0.f};
        if (gn < n_nodes) {
            if constexpr (sizeof(T) == 2) {
                ushort4v v = *(const ushort4v*)(A1 + (size_t)gn * DD + k0);
                #pragma unroll
                for (int j = 0; j < 4; ++j) va[j] = bf2f(v[j]);
            } else {
                float4 v = *(const float4*)(A1 + (size_t)gn * DD + k0);
                va[0] = v.x; va[1] = v.y; va[2] = v.z; va[3] = v.w;
            }
        }
        float* p = As1 + n * ROW + k0;
        p[0] = va[0]; p[1] = va[1]; p[2] = va[2]; p[3] = va[3];
        if (A2) {
            float vc[4] = {0.f, 0.f, 0.f, 0.f};
            if (gn < n_nodes) {
                if constexpr (sizeof(T) == 2) {
                    ushort4v v = *(const ushort4v*)(A2 + (size_t)gn * DD + k0);
                    #pragma unroll
                    for (int j = 0; j < 4; ++j) vc[j] = bf2f(v[j]);
                } else {
                    float4 v = *(const float4*)(A2 + (size_t)gn * DD + k0);
                    vc[0] = v.x; vc[1] = v.y; vc[2] = v.z; vc[3] = v.w;
                }
            }
            float* p2 = As2 + n * ROW + k0;
            p2[0] = vc[0]; p2[1] = vc[1]; p2[2] = vc[2]; p2[3] = vc[3];
        }
    }
    __syncthreads();

    float acc[4][4];
    #pragma unroll
    for (int j = 0; j < 4; ++j) {
        float bj = bias[tx * 4 + j];
        #pragma unroll
        for (int i = 0; i < 4; ++i) acc[i][j] = bj;
    }

    const float* a_row = As1 + (ty * 4) * ROW;
    const float* w_row = Ws1 + (tx * 4) * ROW;
    #pragma unroll 8
    for (int k = 0; k < DD; ++k) {
        float av[4], wv[4];
        #pragma unroll
        for (int i = 0; i < 4; ++i) av[i] = a_row[i * ROW + k];
        #pragma unroll
        for (int j = 0; j < 4; ++j) wv[j] = w_row[j * ROW + k];
        #pragma unroll
        for (int i = 0; i < 4; ++i)
            #pragma unroll
            for (int j = 0; j < 4; ++j) acc[i][j] += av[i] * wv[j];
    }
    if (A2) {
        const float* a2_row = As2 + (ty * 4) * ROW;
        const float* w2_row = Ws2 + (tx * 4) * ROW;
        #pragma unroll 8
        for (int k = 0; k < DD; ++k) {
            float av[4], wv[4];
            #pragma unroll
            for (int i = 0; i < 4; ++i) av[i] = a2_row[i * ROW + k];
            #pragma unroll
            for (int j = 0; j < 4; ++j) wv[j] = w2_row[j * ROW + k];
            #pragma unroll
            for (int i = 0; i < 4; ++i)
                #pragma unroll
                for (int j = 0; j < 4; ++j) acc[i][j] += av[i] * wv[j];
        }
    }

    #pragma unroll
    for (int i = 0; i < 4; ++i) {
        int n = n_base + ty * 4 + i;
        if (n < n_nodes) {
            float v0 = acc[i][0], v1 = acc[i][1], v2 = acc[i][2], v3 = acc[i][3];
            if (relu) {
                v0 = fmaxf(v0, 0.f); v1 = fmaxf(v1, 0.f);
                v2 = fmaxf(v2, 0.f); v3 = fmaxf(v3, 0.f);
            }
            ushort4v o;
            o[0] = f2bf(v0); o[1] = f2bf(v1); o[2] = f2bf(v2); o[3] = f2bf(v3);
            *(ushort4v*)(out + (size_t)n * DD + tx * 4) = o;
        }
    }
}

// ---------------- preds: 2 edges per wave, bf16 rows ----------------
__global__ void k_pred(const u16* __restrict__ h, const int* __restrict__ eli,
                       int n_label, float* __restrict__ out) {
    int t = threadIdx.x;
    int e = blockIdx.x * 8 + (t >> 5);
    if (e >= n_label) return;
    int g = (t >> 4) & 1;
    int r = t & 15;
    int node = g ? eli[n_label + e] : eli[e];
    ushort4v v = *(const ushort4v*)(h + (size_t)node * DD + r * 4);
    float f0 = bf2f(v[0]), f1 = bf2f(v[1]), f2 = bf2f(v[2]), f3 = bf2f(v[3]);
    float w0 = __shfl_xor(f0, 16, 64);
    float w1 = __shfl_xor(f1, 16, 64);
    float w2 = __shfl_xor(f2, 16, 64);
    float w3 = __shfl_xor(f3, 16, 64);
    float s = f0 * w0 + f1 * w1 + f2 * w2 + f3 * w3;
    #pragma unroll
    for (int off = 1; off < 16; off <<= 1) s += __shfl_xor(s, off, 64);
    if ((t & 31) == 0) out[e] = s;
}

extern "C" void kernel_launch(void* const* d_in, const int* in_sizes, int n_in,
                              void* d_out, int out_size, void* d_ws, size_t ws_size,
                              hipStream_t stream) {
    const float* x     = (const float*)d_in[0];
    const int*   ei    = (const int*)d_in[1];
    const int*   eli   = (const int*)d_in[2];
    const float* W_lin = (const float*)d_in[3];
    const float* b_lin = (const float*)d_in[4];
    const float* Wl1   = (const float*)d_in[5];
    const float* bl1   = (const float*)d_in[6];
    const float* Wr1   = (const float*)d_in[7];
    const float* Wl2   = (const float*)d_in[8];
    const float* bl2   = (const float*)d_in[9];
    const float* Wr2   = (const float*)d_in[10];

    int n_nodes = in_sizes[0] / DD;
    int n_edges = in_sizes[1] / 2;
    int n_label = in_sizes[2] / 2;
    float* out = (float*)d_out;

    int nb = (n_nodes + BW - 1) / BW;     // buckets (196 for 100K)

    char* ws = (char*)d_ws;
    size_t hbytes = (size_t)n_nodes * DD * sizeof(u16);
    u16* mean = (u16*)ws; ws += hbytes;
    u16* hA   = (u16*)ws; ws += hbytes;
    u16* hB   = (u16*)ws; ws += hbytes;
    int* row_start    = (int*)ws; ws += (size_t)((n_nodes + 5) & ~3) * sizeof(int);
    int* bucket_cnt   = (int*)ws; ws += NBMAX * sizeof(int);
    int* bucket_start = (int*)ws; ws += (NBMAX + 4) * sizeof(int);
    int* cursor       = (int*)ws; ws += NBMAX * sizeof(int);
    unsigned* part    = (unsigned*)ws; ws += (size_t)n_edges * sizeof(unsigned);
    int* csr          = (int*)ws; ws += (size_t)n_edges * sizeof(int);

    int nb_chunk = (n_edges + CHUNK - 1) / CHUNK;

    // CSR build (2-level counting sort)
    hipMemsetAsync(bucket_cnt, 0, NBMAX * sizeof(int), stream);
    k_hist<<<nb_chunk, 256, 0, stream>>>(ei, n_edges, bucket_cnt);
    k_bscan<<<1, 256, 0, stream>>>(bucket_cnt, cursor, bucket_start, row_start, nb, n_edges, n_nodes);
    k_part<<<nb_chunk, 256, 0, stream>>>(ei, n_edges, cursor, part);
    k_build<<<nb, 256, 0, stream>>>(part, bucket_start, row_start, csr, n_nodes);

    int nb_gemm   = (n_nodes + DD - 1) / DD;
    int nb_gather = (n_nodes + 3) / 4;
    int nb_pred   = (n_label + 7) / 8;

    // layer 0: node linear (fp32 x -> bf16 h0)
    k_gemm<float><<<nb_gemm, 256, 0, stream>>>(x, nullptr, W_lin, nullptr, b_lin, hA, n_nodes, 0);

    // conv1
    k_gather<<<nb_gather, 256, 0, stream>>>(hA, row_start, csr, mean, n_nodes);
    k_gemm<u16><<<nb_gemm, 256, 0, stream>>>(mean, hA, Wl1, Wr1, bl1, hB, n_nodes, 1);

    // conv2
    k_gather<<<nb_gather, 256, 0, stream>>>(hB, row_start, csr, mean, n_nodes);
    k_gemm<u16><<<nb_gemm, 256, 0, stream>>>(mean, hB, Wl2, Wr2, bl2, hA, n_nodes, 0);

    // edge classifier
    k_pred<<<nb_pred, 256, 0, stream>>>(hA, eli, n_label, out);
}

// Round 6
// 286.245 us; speedup vs baseline: 5.2031x; 1.2161x over previous
//
#include <hip/hip_runtime.h>

#define DD 64
#define BW 512            // nodes per bucket (dst >> 9)
#define NBMAX 256         // supports n_nodes <= 131072
#define CAP 8192          // LDS csr staging capacity per bucket
#define CHUNK 2048        // edges per block in hist/part

typedef unsigned short u16;
typedef u16 ushort4v __attribute__((ext_vector_type(4)));
typedef u16 ushort8v __attribute__((ext_vector_type(8)));
typedef short s16x8 __attribute__((ext_vector_type(8)));
typedef float f32x4 __attribute__((ext_vector_type(4)));

__device__ __forceinline__ float bf2f(u16 u) {
    union { unsigned u32; float f; } x; x.u32 = (unsigned)u << 16; return x.f;
}
__device__ __forceinline__ u16 f2bf(float f) {
    union { float f; unsigned u; } x; x.f = f;
    unsigned r = (x.u + 0x7fffu + ((x.u >> 16) & 1u)) >> 16;   // RTNE
    return (u16)r;
}

// ---------------- pass A: bucket histogram ----------------
__global__ void k_hist(const int* __restrict__ ei, int n_edges, int* __restrict__ bucket_cnt) {
    __shared__ int hist[NBMAX];
    int t = threadIdx.x;
    hist[t] = 0;
    __syncthreads();
    int c0 = blockIdx.x * CHUNK;
    int c1 = min(n_edges, c0 + CHUNK);
    for (int e = c0 + t; e < c1; e += 256)
        atomicAdd(&hist[ei[n_edges + e] >> 9], 1);
    __syncthreads();
    if (hist[t] > 0) atomicAdd(&bucket_cnt[t], hist[t]);
}

// ---------------- pass B: scan bucket totals ----------------
__global__ void k_bscan(const int* __restrict__ bucket_cnt, int* __restrict__ cursor,
                        int* __restrict__ bucket_start, int* __restrict__ row_start,
                        int nb, int n_edges, int n_nodes) {
    __shared__ int lds[256];
    int t = threadIdx.x;
    lds[t] = (t < nb) ? bucket_cnt[t] : 0;
    __syncthreads();
    for (int off = 1; off < 256; off <<= 1) {
        int x = (t >= off) ? lds[t - off] : 0;
        __syncthreads();
        if (t >= off) lds[t] += x;
        __syncthreads();
    }
    int excl = (t == 0) ? 0 : lds[t - 1];
    if (t < nb) { bucket_start[t] = excl; cursor[t] = excl; }
    if (t == 0) { bucket_start[nb] = n_edges; row_start[n_nodes] = n_edges; }
}

// ---------------- pass C: partition edges into buckets ----------------
// part[pos] = (src << 9) | (dst & 511)
__global__ void k_part(const int* __restrict__ ei, int n_edges,
                       int* __restrict__ cursor, unsigned* __restrict__ part) {
    __shared__ int hist[NBMAX];
    __shared__ int curs[NBMAX];
    int t = threadIdx.x;
    hist[t] = 0;
    __syncthreads();
    int c0 = blockIdx.x * CHUNK;
    int c1 = min(n_edges, c0 + CHUNK);
    for (int e = c0 + t; e < c1; e += 256)
        atomicAdd(&hist[ei[n_edges + e] >> 9], 1);
    __syncthreads();
    int base = 0;
    if (hist[t] > 0) base = atomicAdd(&cursor[t], hist[t]);
    curs[t] = base;
    __syncthreads();
    for (int e = c0 + t; e < c1; e += 256) {
        int dst = ei[n_edges + e];
        int src = ei[e];
        int b = dst >> 9;
        int pos = atomicAdd(&curs[b], 1);
        part[pos] = ((unsigned)src << 9) | (unsigned)(dst & 511);
    }
}

// ---------------- pass D: per-bucket row_start + csr build in LDS ----------------
__global__ __launch_bounds__(256) void k_build(const unsigned* __restrict__ part,
                        const int* __restrict__ bucket_start,
                        int* __restrict__ row_start, int* __restrict__ csr, int n_nodes) {
    __shared__ int cnt_l[BW];
    __shared__ int sc[BW];
    __shared__ unsigned csr_l[CAP];
    int t = threadIdx.x;
    int b = blockIdx.x;
    int beg = bucket_start[b], end = bucket_start[b + 1];
    int size = end - beg;

    cnt_l[t] = 0; cnt_l[256 + t] = 0;
    __syncthreads();
    for (int j = beg + t; j < end; j += 256)
        atomicAdd(&cnt_l[part[j] & 511], 1);
    __syncthreads();
    int v0 = cnt_l[t], v1 = cnt_l[256 + t];
    sc[t] = v0; sc[256 + t] = v1;
    cnt_l[t] = 0; cnt_l[256 + t] = 0;
    __syncthreads();
    for (int off = 1; off < 256; off <<= 1) {
        int a = (t >= off) ? sc[t - off] : 0;
        int c = (t >= off) ? sc[256 + t - off] : 0;
        __syncthreads();
        if (t >= off) { sc[t] += a; sc[256 + t] += c; }
        __syncthreads();
    }
    int tot0 = sc[255];
    __syncthreads();
    sc[256 + t] += tot0;
    __syncthreads();
    {
        int n0 = b * BW + t;
        if (n0 < n_nodes) row_start[n0] = beg + ((t == 0) ? 0 : sc[t - 1]);
        int n1 = b * BW + 256 + t;
        if (n1 < n_nodes) row_start[n1] = beg + sc[255 + t];
    }
    if (size <= CAP) {
        for (int j = beg + t; j < end; j += 256) {
            unsigned p = part[j];
            int dl = (int)(p & 511u);
            int pos = ((dl == 0) ? 0 : sc[dl - 1]) + atomicAdd(&cnt_l[dl], 1);
            csr_l[pos] = p >> 9;
        }
        __syncthreads();
        for (int i = t; i < size; i += 256) csr[beg + i] = (int)csr_l[i];
    } else {
        for (int j = beg + t; j < end; j += 256) {
            unsigned p = part[j];
            int dl = (int)(p & 511u);
            int pos = ((dl == 0) ? 0 : sc[dl - 1]) + atomicAdd(&cnt_l[dl], 1);
            csr[beg + pos] = (int)(p >> 9);
        }
    }
}

// ---------------- convert 5 weight matrices fp32 -> bf16 ----------------
__global__ void k_cvtw(const float* __restrict__ w0, const float* __restrict__ w1,
                       const float* __restrict__ w2, const float* __restrict__ w3,
                       const float* __restrict__ w4, u16* __restrict__ wb) {
    int i = blockIdx.x * 256 + threadIdx.x;   // grid = 5*4096/256 = 80 blocks
    int mat = i >> 12, off = i & 4095;
    const float* src = (mat == 0) ? w0 : (mat == 1) ? w1 : (mat == 2) ? w2 : (mat == 3) ? w3 : w4;
    wb[i] = f2bf(src[off]);
}

// ---------------- gather-mean: one wave per node, bf16 rows (128 B) ----------------
__global__ void k_gather(const u16* __restrict__ h, const int* __restrict__ row_start,
                         const int* __restrict__ csr, u16* __restrict__ mean, int n_nodes) {
    int t = threadIdx.x;
    int l = t & 63;
    int r = l & 7;
    int q = l >> 3;
    int n = blockIdx.x * 4 + (t >> 6);
    if (n >= n_nodes) return;
    int beg = row_start[n], end = row_start[n + 1];
    float a[8];
    #pragma unroll
    for (int i = 0; i < 8; ++i) a[i] = 0.f;
    for (int j = beg + q; j < end; j += 8) {
        int s = csr[j];
        ushort8v v = *(const ushort8v*)(h + (size_t)s * DD + r * 8);
        #pragma unroll
        for (int i = 0; i < 8; ++i) a[i] += bf2f(v[i]);
    }
    #pragma unroll
    for (int off = 8; off < 64; off <<= 1) {
        #pragma unroll
        for (int i = 0; i < 8; ++i) a[i] += __shfl_xor(a[i], off, 64);
    }
    int deg = end - beg;
    float inv = (deg > 0) ? 1.0f / (float)deg : 0.0f;
    if (q == 0) {
        ushort8v o;
        #pragma unroll
        for (int i = 0; i < 8; ++i) o[i] = f2bf(a[i] * inv);
        *(ushort8v*)(mean + (size_t)n * DD + r * 8) = o;
    }
}

// ---------------- MFMA a-fragment loaders ----------------
__device__ __forceinline__ s16x8 afrag_bf(const u16* p) {
    return *(const s16x8*)p;
}
__device__ __forceinline__ s16x8 afrag_f32(const float* p) {
    float4 v0 = *(const float4*)p;
    float4 v1 = *(const float4*)(p + 4);
    s16x8 r;
    r[0] = (short)f2bf(v0.x); r[1] = (short)f2bf(v0.y);
    r[2] = (short)f2bf(v0.z); r[3] = (short)f2bf(v0.w);
    r[4] = (short)f2bf(v1.x); r[5] = (short)f2bf(v1.y);
    r[6] = (short)f2bf(v1.z); r[7] = (short)f2bf(v1.w);
    return r;
}

// ------- out(bf16) = [relu]( A1 @ W1^T + bias [+ A2 @ W2^T] ) via MFMA -------
// block = 4 waves x 16 nodes = 64 nodes; wave does 4 n-tiles of 16 dims.
// A-frag: A[m=lane&15][k=quad*8+j]; B-frag: W[n=lane&15][k=quad*8+j];
// C/D: row=quad*4+reg (node), col=lane&15 (dim).  [m89/m91/m120 layouts]
template <typename T>
__global__ __launch_bounds__(256) void k_gemm(
    const T* __restrict__ A1, const u16* __restrict__ A2,
    const u16* __restrict__ W1, const u16* __restrict__ W2,
    const float* __restrict__ bias, u16* __restrict__ out,
    int n_nodes, int relu) {
    int t = threadIdx.x;
    int lane = t & 63;
    int col = lane & 15;
    int quad = lane >> 4;
    int m0 = blockIdx.x * 64 + (t >> 6) * 16;
    int arow = m0 + col;
    if (arow > n_nodes - 1) arow = n_nodes - 1;   // clamp (no OOB read; stores guarded)

    f32x4 acc[4];
    #pragma unroll
    for (int nt = 0; nt < 4; ++nt) acc[nt] = (f32x4){0.f, 0.f, 0.f, 0.f};

    #pragma unroll
    for (int ks = 0; ks < 2; ++ks) {
        int k0 = ks * 32 + quad * 8;
        s16x8 a;
        if constexpr (sizeof(T) == 2) a = afrag_bf((const u16*)A1 + (size_t)arow * DD + k0);
        else                          a = afrag_f32((const float*)A1 + (size_t)arow * DD + k0);
        #pragma unroll
        for (int nt = 0; nt < 4; ++nt) {
            s16x8 b = *(const s16x8*)(W1 + (nt * 16 + col) * DD + k0);
            acc[nt] = __builtin_amdgcn_mfma_f32_16x16x32_bf16(a, b, acc[nt], 0, 0, 0);
        }
    }
    if (A2) {
        #pragma unroll
        for (int ks = 0; ks < 2; ++ks) {
            int k0 = ks * 32 + quad * 8;
            s16x8 a = afrag_bf(A2 + (size_t)arow * DD + k0);
            #pragma unroll
            for (int nt = 0; nt < 4; ++nt) {
                s16x8 b = *(const s16x8*)(W2 + (nt * 16 + col) * DD + k0);
                acc[nt] = __builtin_amdgcn_mfma_f32_16x16x32_bf16(a, b, acc[nt], 0, 0, 0);
            }
        }
    }

    int mbase = m0 + quad * 4;
    #pragma unroll
    for (int nt = 0; nt < 4; ++nt) {
        float bv = bias[nt * 16 + col];
        #pragma unroll
        for (int i = 0; i < 4; ++i) {
            int m = mbase + i;
            if (m < n_nodes) {
                float v = acc[nt][i] + bv;
                if (relu) v = fmaxf(v, 0.f);
                out[(size_t)m * DD + nt * 16 + col] = f2bf(v);
            }
        }
    }
}

// ---------------- preds: 2 edges per wave, bf16 rows ----------------
__global__ void k_pred(const u16* __restrict__ h, const int* __restrict__ eli,
                       int n_label, float* __restrict__ out) {
    int t = threadIdx.x;
    int e = blockIdx.x * 8 + (t >> 5);
    if (e >= n_label) return;
    int g = (t >> 4) & 1;
    int r = t & 15;
    int node = g ? eli[n_label + e] : eli[e];
    ushort4v v = *(const ushort4v*)(h + (size_t)node * DD + r * 4);
    float f0 = bf2f(v[0]), f1 = bf2f(v[1]), f2 = bf2f(v[2]), f3 = bf2f(v[3]);
    float w0 = __shfl_xor(f0, 16, 64);
    float w1 = __shfl_xor(f1, 16, 64);
    float w2 = __shfl_xor(f2, 16, 64);
    float w3 = __shfl_xor(f3, 16, 64);
    float s = f0 * w0 + f1 * w1 + f2 * w2 + f3 * w3;
    #pragma unroll
    for (int off = 1; off < 16; off <<= 1) s += __shfl_xor(s, off, 64);
    if ((t & 31) == 0) out[e] = s;
}

extern "C" void kernel_launch(void* const* d_in, const int* in_sizes, int n_in,
                              void* d_out, int out_size, void* d_ws, size_t ws_size,
                              hipStream_t stream) {
    const float* x     = (const float*)d_in[0];
    const int*   ei    = (const int*)d_in[1];
    const int*   eli   = (const int*)d_in[2];
    const float* W_lin = (const float*)d_in[3];
    const float* b_lin = (const float*)d_in[4];
    const float* Wl1   = (const float*)d_in[5];
    const float* bl1   = (const float*)d_in[6];
    const float* Wr1   = (const float*)d_in[7];
    const float* Wl2   = (const float*)d_in[8];
    const float* bl2   = (const float*)d_in[9];
    const float* Wr2   = (const float*)d_in[10];

    int n_nodes = in_sizes[0] / DD;
    int n_edges = in_sizes[1] / 2;
    int n_label = in_sizes[2] / 2;
    float* out = (float*)d_out;

    int nb = (n_nodes + BW - 1) / BW;     // buckets (196 for 100K)

    char* ws = (char*)d_ws;
    size_t hbytes = (size_t)n_nodes * DD * sizeof(u16);
    u16* mean = (u16*)ws; ws += hbytes;
    u16* hA   = (u16*)ws; ws += hbytes;
    u16* hB   = (u16*)ws; ws += hbytes;
    int* row_start    = (int*)ws; ws += (size_t)((n_nodes + 5) & ~3) * sizeof(int);
    int* bucket_cnt   = (int*)ws; ws += NBMAX * sizeof(int);
    int* bucket_start = (int*)ws; ws += (NBMAX + 4) * sizeof(int);
    int* cursor       = (int*)ws; ws += NBMAX * sizeof(int);
    u16* wb           = (u16*)ws; ws += 5 * DD * DD * sizeof(u16);
    unsigned* part    = (unsigned*)ws; ws += (size_t)n_edges * sizeof(unsigned);
    int* csr          = (int*)ws; ws += (size_t)n_edges * sizeof(int);

    int nb_chunk = (n_edges + CHUNK - 1) / CHUNK;

    // weight conversion (independent of CSR chain)
    k_cvtw<<<80, 256, 0, stream>>>(W_lin, Wl1, Wr1, Wl2, Wr2, wb);

    // CSR build (2-level counting sort)
    hipMemsetAsync(bucket_cnt, 0, NBMAX * sizeof(int), stream);
    k_hist<<<nb_chunk, 256, 0, stream>>>(ei, n_edges, bucket_cnt);
    k_bscan<<<1, 256, 0, stream>>>(bucket_cnt, cursor, bucket_start, row_start, nb, n_edges, n_nodes);
    k_part<<<nb_chunk, 256, 0, stream>>>(ei, n_edges, cursor, part);
    k_build<<<nb, 256, 0, stream>>>(part, bucket_start, row_start, csr, n_nodes);

    int nb_gemm   = (n_nodes + 63) / 64;
    int nb_gather = (n_nodes + 3) / 4;
    int nb_pred   = (n_label + 7) / 8;

    // layer 0: node linear (fp32 x -> bf16 h0) via MFMA
    k_gemm<float><<<nb_gemm, 256, 0, stream>>>(x, nullptr, wb, nullptr, b_lin, hA, n_nodes, 0);

    // conv1
    k_gather<<<nb_gather, 256, 0, stream>>>(hA, row_start, csr, mean, n_nodes);
    k_gemm<u16><<<nb_gemm, 256, 0, stream>>>(mean, hA, wb + 4096, wb + 2 * 4096, bl1, hB, n_nodes, 1);

    // conv2
    k_gather<<<nb_gather, 256, 0, stream>>>(hB, row_start, csr, mean, n_nodes);
    k_gemm<u16><<<nb_gemm, 256, 0, stream>>>(mean, hB, wb + 3 * 4096, wb + 4 * 4096, bl2, hA, n_nodes, 0);

    // edge classifier
    k_pred<<<nb_pred, 256, 0, stream>>>(hA, eli, n_label, out);
}